// Round 1
// baseline (264.616 us; speedup 1.0000x reference)
//
#include <hip/hip_runtime.h>
#include <math.h>

namespace {

constexpr int BATCH = 2;
constexpr int HH = 48;
constexpr int WW = 48;
constexpr int LL = HH * WW;          // 2304
constexpr int DM = 96;
constexpr int DI = 192;
constexpr int KK = 4;
constexpr int NST = 16;              // D_STATE
constexpr int DTR = 6;               // DT_RANK
constexpr int CDIM = DTR + 2 * NST;  // 38
constexpr int BL = BATCH * LL;       // 4608

__device__ __forceinline__ int pos1(int l) { return (l % WW) * HH + (l / WW); }
__device__ __forceinline__ float siluf(float v) { return v / (1.f + __expf(-v)); }

// ---------------------------------------------------------------------------
// K1: in_proj GEMM  out[bl][e] = sum_c x[bl][c] * W[e][c],  e in [0,384)
// e<192 -> xc_cl (B,L,192) ; e>=192 -> silu(z) (B,L,192)
// block: 384 threads, tile = 16 rows (bl), all 384 e.
// thread t: te = t%96 owns e in {te, te+96, te+192, te+288}; tl=t/96 owns 4 rows.
// ---------------------------------------------------------------------------
__global__ __launch_bounds__(384) void k_inproj(const float* __restrict__ x,
                                                const float* __restrict__ W,
                                                float* __restrict__ xc_cl,
                                                float* __restrict__ z_silu) {
  __shared__ float xs[16][97];
  const int bl0 = blockIdx.x * 16;
  const int t = threadIdx.x;
  for (int idx = t; idx < 16 * 96; idx += 384) {
    xs[idx / 96][idx % 96] = x[bl0 * 96 + idx];
  }
  __syncthreads();
  const int te = t % 96;
  const int l0 = (t / 96) * 4;
  float acc[4][4];
#pragma unroll
  for (int j = 0; j < 4; ++j)
#pragma unroll
    for (int r = 0; r < 4; ++r) acc[j][r] = 0.f;

  for (int ic = 0; ic < 96; ic += 4) {
    const float4 w0 = *(const float4*)(W + (te + 0) * 96 + ic);
    const float4 w1 = *(const float4*)(W + (te + 96) * 96 + ic);
    const float4 w2 = *(const float4*)(W + (te + 192) * 96 + ic);
    const float4 w3 = *(const float4*)(W + (te + 288) * 96 + ic);
#pragma unroll
    for (int r = 0; r < 4; ++r) {
      const float x0 = xs[l0 + r][ic + 0];
      const float x1 = xs[l0 + r][ic + 1];
      const float x2 = xs[l0 + r][ic + 2];
      const float x3 = xs[l0 + r][ic + 3];
      acc[0][r] += w0.x * x0 + w0.y * x1 + w0.z * x2 + w0.w * x3;
      acc[1][r] += w1.x * x0 + w1.y * x1 + w1.z * x2 + w1.w * x3;
      acc[2][r] += w2.x * x0 + w2.y * x1 + w2.z * x2 + w2.w * x3;
      acc[3][r] += w3.x * x0 + w3.y * x1 + w3.z * x2 + w3.w * x3;
    }
  }
#pragma unroll
  for (int r = 0; r < 4; ++r) {
    const int bl = bl0 + l0 + r;
    xc_cl[bl * DI + te] = acc[0][r];
    xc_cl[bl * DI + te + 96] = acc[1][r];
    z_silu[bl * DI + te] = siluf(acc[2][r]);
    z_silu[bl * DI + te + 96] = siluf(acc[3][r]);
  }
}

// ---------------------------------------------------------------------------
// K2: depthwise 3x3 conv (cross-correlation) + bias + SiLU.
// Writes channels-last (for K3 staging) and two (B,D,L) row-major layouts
// (identity and transposed) for scan staging.
// ---------------------------------------------------------------------------
__global__ __launch_bounds__(256) void k_conv(const float* __restrict__ xc_cl,
                                              const float* __restrict__ cw,
                                              const float* __restrict__ cb,
                                              float* __restrict__ xconv_cl,
                                              float* __restrict__ xconv_dl,
                                              float* __restrict__ xconvT_dl) {
  const int tg = blockIdx.x * 256 + threadIdx.x;  // exact: B*L*DI = 3456*256
  const int d = tg % DI;
  const int bl = tg / DI;
  const int l = bl % LL;
  const int b = bl / LL;
  const int h = l / WW, w = l % WW;
  float acc = cb[d];
#pragma unroll
  for (int kh = 0; kh < 3; ++kh) {
    const int h2 = h + kh - 1;
    if (h2 < 0 || h2 >= HH) continue;
#pragma unroll
    for (int kw = 0; kw < 3; ++kw) {
      const int w2 = w + kw - 1;
      if (w2 < 0 || w2 >= WW) continue;
      acc += xc_cl[(b * LL + h2 * WW + w2) * DI + d] * cw[d * 9 + kh * 3 + kw];
    }
  }
  const float u = siluf(acc);
  xconv_cl[bl * DI + d] = u;
  xconv_dl[(b * DI + d) * LL + l] = u;
  xconvT_dl[(b * DI + d) * LL + pos1(l)] = u;
}

// ---------------------------------------------------------------------------
// K3: x_dbl (38x192 per site) + delta projection + softplus, fused.
// block per (b, k, 64-l tile). u-tile staged in LDS with +1 pad.
// Outputs: Bs,Cs in (B,K,L,16); delta in (B,K,D,L) scan order.
// ---------------------------------------------------------------------------
__global__ __launch_bounds__(256) void k_xdbl(const float* __restrict__ xconv_cl,
                                              const float* __restrict__ xpw,
                                              const float* __restrict__ dtw,
                                              const float* __restrict__ dtb,
                                              float* __restrict__ Bs,
                                              float* __restrict__ Cs,
                                              float* __restrict__ delta) {
  __shared__ float us[64][193];
  __shared__ float dts[DTR][64];
  const int lt = blockIdx.x % (LL / 64);
  const int k = (blockIdx.x / (LL / 64)) % KK;
  const int b = blockIdx.x / ((LL / 64) * KK);
  const int l0 = lt * 64;
  const int t = threadIdx.x;
  const int bk = b * KK + k;

  for (int idx = t; idx < 64 * DI; idx += 256) {
    const int ll = idx / DI, d = idx % DI;
    const int l = l0 + ll;
    const int lidx = (k >= 2) ? (LL - 1 - l) : l;
    const int p = (k & 1) ? pos1(lidx) : lidx;
    us[ll][d] = xconv_cl[(b * LL + p) * DI + d];
  }
  __syncthreads();
  {
    const int cg = __builtin_amdgcn_readfirstlane((int)(t >> 6));
    const int ll = t & 63;
#pragma unroll
    for (int j = 0; j < 10; ++j) {
      const int c = cg + 4 * j;
      if (c < CDIM) {
        const float* wr = xpw + (k * CDIM + c) * DI;
        float acc = 0.f;
#pragma unroll 8
        for (int d = 0; d < DI; ++d) acc += wr[d] * us[ll][d];
        if (c < DTR)
          dts[c][ll] = acc;
        else if (c < DTR + NST)
          Bs[(bk * LL + l0 + ll) * NST + (c - DTR)] = acc;
        else
          Cs[(bk * LL + l0 + ll) * NST + (c - DTR - NST)] = acc;
      }
    }
  }
  __syncthreads();
  {
    const int dg = __builtin_amdgcn_readfirstlane((int)(t >> 6));
    const int ll = t & 63;
#pragma unroll 4
    for (int j = 0; j < 48; ++j) {
      const int d = dg + 4 * j;
      float acc = dtb[k * DI + d];
#pragma unroll
      for (int r = 0; r < DTR; ++r) acc += dtw[(k * DI + d) * DTR + r] * dts[r][ll];
      const float sp = fmaxf(acc, 0.f) + log1pf(__expf(-fabsf(acc)));
      delta[(bk * DI + d) * LL + l0 + ll] = sp;
    }
  }
}

// ---------------------------------------------------------------------------
// K5: selective scan. Block per (b,k,d): 256 threads = 16 chunks x 16 states.
// Phase 1: per-chunk (prod a, affine b). LDS combine. Phase 2: replay with
// corrected initial state, per-step shfl_xor reduce over the 16 states.
// out_y layout (B,K,L,D) so K6 reads are coalesced; D*u folded in here.
// ---------------------------------------------------------------------------
__global__ __launch_bounds__(256) void k_scan(const float* __restrict__ delta,
                                              const float* __restrict__ xconv_dl,
                                              const float* __restrict__ xconvT_dl,
                                              const float* __restrict__ Bs,
                                              const float* __restrict__ Cs,
                                              const float* __restrict__ A_logs,
                                              const float* __restrict__ Dvec,
                                              float* __restrict__ out_y) {
  __shared__ float dl_s[LL];
  __shared__ float u_s[LL];
  __shared__ float Ps[16][16];
  __shared__ float Qs[16][16];
  const int d = blockIdx.x % DI;
  const int k = (blockIdx.x / DI) % KK;
  const int b = blockIdx.x / (DI * KK);
  const int bk = b * KK + k;
  const int t = threadIdx.x;

  const float* drow = delta + (bk * DI + d) * LL;
  const float* urow = ((k & 1) ? xconvT_dl : xconv_dl) + (b * DI + d) * LL;
  for (int idx = t; idx < LL; idx += 256) {
    dl_s[idx] = drow[idx];
    u_s[(k >= 2) ? (LL - 1 - idx) : idx] = urow[idx];
  }
  __syncthreads();

  const int chunk = t >> 4;
  const int n = t & 15;
  constexpr int Lc = LL / 16;  // 144
  const int l0 = chunk * Lc;
  const float A = -__expf(A_logs[(k * DI + d) * NST + n]);
  const float Al2 = A * 1.4426950408889634f;
  const float Dv = Dvec[k * DI + d];
  const float* Brow = Bs + (bk * LL) * NST + n;
  const float* Crow = Cs + (bk * LL) * NST + n;

  float P = 1.f, Q = 0.f;
#pragma unroll 4
  for (int l = l0; l < l0 + Lc; ++l) {
    const float dl = dl_s[l];
    const float a = exp2f(dl * Al2);
    const float bb = dl * u_s[l] * Brow[l * NST];
    P *= a;
    Q = fmaf(a, Q, bb);
  }
  Ps[chunk][n] = P;
  Qs[chunk][n] = Q;
  __syncthreads();
  float h = 0.f;
  for (int cc = 0; cc < chunk; ++cc) h = fmaf(Ps[cc][n], h, Qs[cc][n]);

  float* yrow = out_y + (bk * LL) * DI + d;
#pragma unroll 4
  for (int l = l0; l < l0 + Lc; ++l) {
    const float dl = dl_s[l];
    const float u = u_s[l];
    const float a = exp2f(dl * Al2);
    const float bb = dl * u * Brow[l * NST];
    h = fmaf(a, h, bb);
    float ts = h * Crow[l * NST];
    ts += __shfl_xor(ts, 1, 64);
    ts += __shfl_xor(ts, 2, 64);
    ts += __shfl_xor(ts, 4, 64);
    ts += __shfl_xor(ts, 8, 64);
    if (n == 0) yrow[l * DI] = fmaf(Dv, u, ts);
  }
}

// ---------------------------------------------------------------------------
// K6: combine 4 directions + LayerNorm + silu(z) gate + out_proj. Block per
// (b, pixel p); 256 threads (192 active for LN, 192 for split-dot proj).
// ---------------------------------------------------------------------------
__global__ __launch_bounds__(256) void k_final(const float* __restrict__ out_y,
                                               const float* __restrict__ z_silu,
                                               const float* __restrict__ g,
                                               const float* __restrict__ bta,
                                               const float* __restrict__ opw,
                                               float* __restrict__ out) {
  __shared__ float yn[DI];
  __shared__ float part[DI];
  __shared__ float rs[4], rq[4];
  const int p = blockIdx.x % LL;
  const int b = blockIdx.x / LL;
  const int t = threadIdx.x;
  const int p1 = pos1(p);

  float yv = 0.f;
  if (t < DI) {
    const float* oy = out_y + b * KK * LL * DI;
    yv = oy[(0 * LL + p) * DI + t] + oy[(1 * LL + p1) * DI + t] +
         oy[(2 * LL + (LL - 1 - p)) * DI + t] + oy[(3 * LL + (LL - 1 - p1)) * DI + t];
  }
  float s1 = yv, s2 = yv * yv;
#pragma unroll
  for (int o = 32; o >= 1; o >>= 1) {
    s1 += __shfl_xor(s1, o, 64);
    s2 += __shfl_xor(s2, o, 64);
  }
  if ((t & 63) == 0) {
    rs[t >> 6] = s1;
    rq[t >> 6] = s2;
  }
  __syncthreads();
  const float sum = rs[0] + rs[1] + rs[2] + rs[3];
  const float sq = rq[0] + rq[1] + rq[2] + rq[3];
  const float mu = sum * (1.f / DI);
  const float var = sq * (1.f / DI) - mu * mu;
  const float inv = rsqrtf(var + 1e-5f);
  if (t < DI) {
    const float v = (yv - mu) * inv * g[t] + bta[t];
    yn[t] = v * z_silu[(b * LL + p) * DI + t];
  }
  __syncthreads();
  if (t < DI) {
    const int half = (t >= 96) ? 1 : 0;
    const int c = t - half * 96;
    const float* wr = opw + c * DI + half * 96;
    const float* yr = yn + half * 96;
    float acc = 0.f;
#pragma unroll 8
    for (int i = 0; i < 96; ++i) acc += wr[i] * yr[i];
    part[t] = acc;
  }
  __syncthreads();
  if (t < 96) out[(b * LL + p) * DM + t] = part[t] + part[t + 96];
}

}  // namespace

extern "C" void kernel_launch(void* const* d_in, const int* in_sizes, int n_in,
                              void* d_out, int out_size, void* d_ws, size_t ws_size,
                              hipStream_t stream) {
  (void)in_sizes; (void)n_in; (void)out_size; (void)ws_size;
  const float* x = (const float*)d_in[0];
  const float* ipw = (const float*)d_in[1];
  const float* cw = (const float*)d_in[2];
  const float* cb = (const float*)d_in[3];
  const float* xpw = (const float*)d_in[4];
  const float* dtw = (const float*)d_in[5];
  const float* dtb = (const float*)d_in[6];
  const float* alog = (const float*)d_in[7];
  const float* dsv = (const float*)d_in[8];
  const float* ong = (const float*)d_in[9];
  const float* onb = (const float*)d_in[10];
  const float* opw = (const float*)d_in[11];

  float* ws = (float*)d_ws;
  float* xc_cl = ws;    ws += BL * DI;
  float* z_silu = ws;   ws += BL * DI;
  float* xconv_cl = ws; ws += BL * DI;
  float* xconv_dl = ws; ws += BL * DI;
  float* xconvT = ws;   ws += BL * DI;
  float* Bsb = ws;      ws += BATCH * KK * LL * NST;
  float* Csb = ws;      ws += BATCH * KK * LL * NST;
  float* delta = ws;    ws += BATCH * KK * DI * LL;
  float* out_y = ws;

  hipLaunchKernelGGL(k_inproj, dim3(BL / 16), dim3(384), 0, stream, x, ipw, xc_cl, z_silu);
  hipLaunchKernelGGL(k_conv, dim3(BATCH * LL * DI / 256), dim3(256), 0, stream,
                     xc_cl, cw, cb, xconv_cl, xconv_dl, xconvT);
  hipLaunchKernelGGL(k_xdbl, dim3(BATCH * KK * (LL / 64)), dim3(256), 0, stream,
                     xconv_cl, xpw, dtw, dtb, Bsb, Csb, delta);
  hipLaunchKernelGGL(k_scan, dim3(BATCH * KK * DI), dim3(256), 0, stream,
                     delta, xconv_dl, xconvT, Bsb, Csb, alog, dsv, out_y);
  hipLaunchKernelGGL(k_final, dim3(BL), dim3(256), 0, stream, out_y, z_silu, ong, onb, opw,
                     (float*)d_out);
}

// Round 2
// 206.808 us; speedup vs baseline: 1.2795x; 1.2795x over previous
//
#include <hip/hip_runtime.h>
#include <math.h>

namespace {

constexpr int BATCH = 2;
constexpr int HH = 48;
constexpr int WW = 48;
constexpr int LL = HH * WW;          // 2304
constexpr int DM = 96;
constexpr int DI = 192;
constexpr int KK = 4;
constexpr int NST = 16;
constexpr int DTR = 6;
constexpr int CDIM = DTR + 2 * NST;  // 38
constexpr int BL = BATCH * LL;       // 4608

__device__ __forceinline__ int pos1(int l) { return (l % WW) * HH + (l / WW); }
__device__ __forceinline__ float siluf(float v) { return v / (1.f + __expf(-v)); }

// ---------------------------------------------------------------------------
// K1: in_proj GEMM (4608x384x96), 64x64 tile, LDS-staged A and W.
// thread (tx,ty): e = e0 + tx + 16j (lane-interleaved -> conflict-free b128),
// rows = r0 + ty*4 + r. Block 0 additionally transposes opw -> opwT.
// ---------------------------------------------------------------------------
__global__ __launch_bounds__(256) void k_inproj(const float* __restrict__ x,
                                                const float* __restrict__ W,
                                                const float* __restrict__ opw,
                                                float* __restrict__ xc,
                                                float* __restrict__ zs,
                                                float* __restrict__ opwT) {
  __shared__ float As[64][100];
  __shared__ float Ws[64][100];
  const int rt = blockIdx.x % 72;
  const int et = blockIdx.x / 72;
  const int t = threadIdx.x;
  const float* ga = x + rt * 64 * 96;
  const float* gw = W + et * 64 * 96;
#pragma unroll
  for (int j = 0; j < 6; ++j) {
    const int i4 = t + 256 * j;  // 1536 float4 per tile
    const float4 va = ((const float4*)ga)[i4];
    const float4 vw = ((const float4*)gw)[i4];
    const int g = i4 * 4;
    const int row = g / 96, col = g % 96;
    *(float4*)&As[row][col] = va;
    *(float4*)&Ws[row][col] = vw;
  }
  __syncthreads();
  const int tx = t & 15, ty = t >> 4;
  float acc[4][4];
#pragma unroll
  for (int j = 0; j < 4; ++j)
#pragma unroll
    for (int r = 0; r < 4; ++r) acc[j][r] = 0.f;

  for (int k = 0; k < 96; k += 4) {
    const float4 w0 = *(const float4*)&Ws[tx][k];
    const float4 w1 = *(const float4*)&Ws[tx + 16][k];
    const float4 w2 = *(const float4*)&Ws[tx + 32][k];
    const float4 w3 = *(const float4*)&Ws[tx + 48][k];
#pragma unroll
    for (int r = 0; r < 4; ++r) {
      const float4 a = *(const float4*)&As[ty * 4 + r][k];
      acc[0][r] += w0.x * a.x + w0.y * a.y + w0.z * a.z + w0.w * a.w;
      acc[1][r] += w1.x * a.x + w1.y * a.y + w1.z * a.z + w1.w * a.w;
      acc[2][r] += w2.x * a.x + w2.y * a.y + w2.z * a.z + w2.w * a.w;
      acc[3][r] += w3.x * a.x + w3.y * a.y + w3.z * a.z + w3.w * a.w;
    }
  }
  const int e0 = et * 64;
#pragma unroll
  for (int j = 0; j < 4; ++j) {
    const int e = e0 + tx + 16 * j;
#pragma unroll
    for (int r = 0; r < 4; ++r) {
      const int bl = rt * 64 + ty * 4 + r;
      if (e < DI)
        xc[bl * DI + e] = acc[j][r];
      else
        zs[bl * DI + (e - DI)] = siluf(acc[j][r]);
    }
  }
  if (blockIdx.x == 0) {
    for (int idx = t; idx < DM * DI; idx += 256) {
      const int c = idx % DM, i = idx / DM;
      opwT[idx] = opw[c * DI + i];  // opwT[i*96+c]
    }
  }
}

// ---------------------------------------------------------------------------
// K2: depthwise 3x3 conv + bias + SiLU. Reads channels-last xc (L1-reused
// across the 8 d-lanes), writes only (B,D,L) row-major, coalesced.
// ---------------------------------------------------------------------------
__global__ __launch_bounds__(256) void k_conv(const float* __restrict__ xc,
                                              const float* __restrict__ cw,
                                              const float* __restrict__ cb,
                                              float* __restrict__ xdl) {
  const int lt = blockIdx.x % 72;
  const int dg = (blockIdx.x / 72) % 24;
  const int b = blockIdx.x / (72 * 24);
  const int t = threadIdx.x;
  const int pl = t & 31, dq = t >> 5;
  const int d = dg * 8 + dq;
  const int l = lt * 32 + pl;
  const int h = l / WW, w = l % WW;
  float wv[9];
#pragma unroll
  for (int i = 0; i < 9; ++i) wv[i] = cw[d * 9 + i];
  float acc = cb[d];
#pragma unroll
  for (int kh = 0; kh < 3; ++kh) {
    const int h2 = h + kh - 1;
    if (h2 < 0 || h2 >= HH) continue;
#pragma unroll
    for (int kw = 0; kw < 3; ++kw) {
      const int w2 = w + kw - 1;
      if (w2 < 0 || w2 >= WW) continue;
      acc += xc[(b * LL + h2 * WW + w2) * DI + d] * wv[kh * 3 + kw];
    }
  }
  xdl[(b * DI + d) * LL + l] = siluf(acc);
}

// ---------------------------------------------------------------------------
// K2b: per-(b,d) 48x48 transpose via LDS: xtr[d][p] = xdl[d][pos1(p)].
// Coalesced read + coalesced write; LDS gather is 2-way (free).
// ---------------------------------------------------------------------------
__global__ __launch_bounds__(256) void k_tr(const float* __restrict__ xdl,
                                            float* __restrict__ xtr) {
  __shared__ float tile[LL];
  const int row = blockIdx.x;  // b*DI + d
  const float* src = xdl + row * LL;
  const int t = threadIdx.x;
  for (int i = t; i < LL; i += 256) tile[i] = src[i];
  __syncthreads();
  float* dst = xtr + row * LL;
  for (int i = t; i < LL; i += 256) dst[i] = tile[pos1(i)];
}

// ---------------------------------------------------------------------------
// K3: x_dbl + delta projection + softplus. us rows stride 196 (=4*49) ->
// conflict-free b128 reads. B/C staged in LDS, stored as one contiguous
// coalesced 4KB block. delta written (B,K,D,L) coalesced.
// ---------------------------------------------------------------------------
__global__ __launch_bounds__(256) void k_xdbl(const float* __restrict__ xdl,
                                              const float* __restrict__ xtr,
                                              const float* __restrict__ xpw,
                                              const float* __restrict__ dtw,
                                              const float* __restrict__ dtb,
                                              float* __restrict__ Bs,
                                              float* __restrict__ Cs,
                                              float* __restrict__ delta) {
  __shared__ float us[64][196];
  __shared__ float dts[DTR][64];
  __shared__ float Bst[64][17];
  __shared__ float Cst[64][17];
  const int lt = blockIdx.x % 36;
  const int k = (blockIdx.x / 36) % KK;
  const int b = blockIdx.x / (36 * KK);
  const int l0 = lt * 64;
  const int t = threadIdx.x;
  const int bk = b * KK + k;
  const float* src = ((k & 1) ? xtr : xdl) + b * DI * LL;
  for (int idx = t; idx < 64 * DI; idx += 256) {
    const int d = idx >> 6, ll = idx & 63;
    const int l = l0 + ll;
    const int m = (k >= 2) ? (LL - 1 - l) : l;
    us[ll][d] = src[d * LL + m];
  }
  __syncthreads();
  {
    const int cg = t >> 6, ll = t & 63;
    const float* usr = &us[ll][0];
#pragma unroll
    for (int j = 0; j < 10; ++j) {
      const int c = cg + 4 * j;
      if (c < CDIM) {
        const float* wr = xpw + (k * CDIM + c) * DI;
        float a0 = 0.f, a1 = 0.f, a2 = 0.f, a3 = 0.f;
#pragma unroll
        for (int d = 0; d < DI; d += 16) {
          const float4 u0 = *(const float4*)(usr + d);
          const float4 u1 = *(const float4*)(usr + d + 4);
          const float4 u2 = *(const float4*)(usr + d + 8);
          const float4 u3 = *(const float4*)(usr + d + 12);
          const float4 w0 = *(const float4*)(wr + d);
          const float4 w1 = *(const float4*)(wr + d + 4);
          const float4 w2 = *(const float4*)(wr + d + 8);
          const float4 w3 = *(const float4*)(wr + d + 12);
          a0 += u0.x * w0.x + u0.y * w0.y + u0.z * w0.z + u0.w * w0.w;
          a1 += u1.x * w1.x + u1.y * w1.y + u1.z * w1.z + u1.w * w1.w;
          a2 += u2.x * w2.x + u2.y * w2.y + u2.z * w2.z + u2.w * w2.w;
          a3 += u3.x * w3.x + u3.y * w3.y + u3.z * w3.z + u3.w * w3.w;
        }
        const float acc = (a0 + a1) + (a2 + a3);
        if (c < DTR)
          dts[c][ll] = acc;
        else if (c < DTR + NST)
          Bst[ll][c - DTR] = acc;
        else
          Cst[ll][c - DTR - NST] = acc;
      }
    }
  }
  __syncthreads();
  for (int idx = t; idx < 64 * NST; idx += 256) {
    const int ll = idx >> 4, n = idx & 15;
    Bs[(bk * LL + l0) * NST + idx] = Bst[ll][n];
    Cs[(bk * LL + l0) * NST + idx] = Cst[ll][n];
  }
  {
    const int dg = t >> 6, ll = t & 63;
#pragma unroll 4
    for (int j = 0; j < 48; ++j) {
      const int d = dg + 4 * j;
      float acc = dtb[k * DI + d];
#pragma unroll
      for (int r = 0; r < DTR; ++r) acc += dtw[(k * DI + d) * DTR + r] * dts[r][ll];
      const float sp = fmaxf(acc, 0.f) + log1pf(__expf(-fabsf(acc)));
      delta[(bk * DI + d) * LL + l0 + ll] = sp;
    }
  }
}

// ---------------------------------------------------------------------------
// K4: selective scan. 1024 threads = 64 chunks x 16 states, Lc=36.
// y buffered in LDS; final store is coalesced into pixel-indexed (BK,D,L)
// (inverse scan-map applied on the LDS-read side).
// ---------------------------------------------------------------------------
__global__ __launch_bounds__(1024) void k_scan(const float* __restrict__ delta,
                                               const float* __restrict__ xdl,
                                               const float* __restrict__ xtr,
                                               const float* __restrict__ Bs,
                                               const float* __restrict__ Cs,
                                               const float* __restrict__ A_logs,
                                               const float* __restrict__ Dvec,
                                               float* __restrict__ out_yp) {
  __shared__ float dl_s[LL];
  __shared__ float u_s[LL];
  __shared__ float y_s[LL];
  __shared__ float Ps[64][16];
  __shared__ float Qs[64][16];
  const int d = blockIdx.x % DI;
  const int k = (blockIdx.x / DI) % KK;
  const int b = blockIdx.x / (DI * KK);
  const int bk = b * KK + k;
  const int t = threadIdx.x;

  const float* drow = delta + (bk * DI + d) * LL;
  const float* urow = ((k & 1) ? xtr : xdl) + (b * DI + d) * LL;
  for (int idx = t; idx < LL; idx += 1024) {
    dl_s[idx] = drow[idx];
    u_s[(k >= 2) ? (LL - 1 - idx) : idx] = urow[idx];
  }
  __syncthreads();

  const int chunk = t >> 4;
  const int n = t & 15;
  constexpr int Lc = LL / 64;  // 36
  const int l0 = chunk * Lc;
  const float A = -__expf(A_logs[(k * DI + d) * NST + n]);
  const float Al2 = A * 1.4426950408889634f;
  const float Dv = Dvec[k * DI + d];
  const float* bp = Bs + (bk * LL + l0) * NST + n;
  const float* cp = Cs + (bk * LL + l0) * NST + n;

  float P = 1.f, Q = 0.f;
#pragma unroll 4
  for (int i = 0; i < Lc; ++i) {
    const float dl = dl_s[l0 + i];
    const float a = exp2f(dl * Al2);
    const float bb = dl * u_s[l0 + i] * bp[i * NST];
    P *= a;
    Q = fmaf(a, Q, bb);
  }
  Ps[chunk][n] = P;
  Qs[chunk][n] = Q;
  __syncthreads();
  float h = 0.f;
  for (int cc = 0; cc < chunk; ++cc) h = fmaf(Ps[cc][n], h, Qs[cc][n]);

#pragma unroll 4
  for (int i = 0; i < Lc; ++i) {
    const float dl = dl_s[l0 + i];
    const float u = u_s[l0 + i];
    const float a = exp2f(dl * Al2);
    const float bb = dl * u * bp[i * NST];
    h = fmaf(a, h, bb);
    float ts = h * cp[i * NST];
    ts += __shfl_xor(ts, 1, 64);
    ts += __shfl_xor(ts, 2, 64);
    ts += __shfl_xor(ts, 4, 64);
    ts += __shfl_xor(ts, 8, 64);
    if (n == 0) y_s[l0 + i] = fmaf(Dv, u, ts);
  }
  __syncthreads();
  float* orow = out_yp + (bk * DI + d) * LL;
  for (int idx = t; idx < LL; idx += 1024) {
    int l;
    if (k == 0) l = idx;
    else if (k == 1) l = pos1(idx);
    else if (k == 2) l = LL - 1 - idx;
    else l = LL - 1 - pos1(idx);
    orow[idx] = y_s[l];
  }
}

// ---------------------------------------------------------------------------
// K6: combine 4 (already pixel-indexed) directions + LN + gate + out_proj
// via opwT (coalesced c-major weight reads).
// ---------------------------------------------------------------------------
__global__ __launch_bounds__(256) void k_final(const float* __restrict__ oyp,
                                               const float* __restrict__ zs,
                                               const float* __restrict__ g,
                                               const float* __restrict__ bta,
                                               const float* __restrict__ opwT,
                                               float* __restrict__ out) {
  __shared__ float yn[DI];
  __shared__ float part[DI];
  __shared__ float rs[4], rq[4];
  const int p = blockIdx.x % LL;
  const int b = blockIdx.x / LL;
  const int t = threadIdx.x;

  float yv = 0.f;
  if (t < DI) {
    const float* base = oyp + b * KK * DI * LL + t * LL + p;
    yv = base[0] + base[DI * LL] + base[2 * DI * LL] + base[3 * DI * LL];
  }
  float s1 = yv, s2 = yv * yv;
#pragma unroll
  for (int o = 32; o >= 1; o >>= 1) {
    s1 += __shfl_xor(s1, o, 64);
    s2 += __shfl_xor(s2, o, 64);
  }
  if ((t & 63) == 0) {
    rs[t >> 6] = s1;
    rq[t >> 6] = s2;
  }
  __syncthreads();
  const float sum = rs[0] + rs[1] + rs[2] + rs[3];
  const float sq = rq[0] + rq[1] + rq[2] + rq[3];
  const float mu = sum * (1.f / DI);
  const float var = sq * (1.f / DI) - mu * mu;
  const float inv = rsqrtf(var + 1e-5f);
  if (t < DI) {
    const float v = (yv - mu) * inv * g[t] + bta[t];
    yn[t] = v * zs[(b * LL + p) * DI + t];
  }
  __syncthreads();
  if (t < DI) {
    const int c = t % 96, half = t / 96;
    float acc = 0.f;
#pragma unroll 8
    for (int i = 0; i < 96; ++i) acc += opwT[(half * 96 + i) * DM + c] * yn[half * 96 + i];
    part[t] = acc;
  }
  __syncthreads();
  if (t < 96) out[(b * LL + p) * DM + t] = part[t] + part[t + 96];
}

}  // namespace

extern "C" void kernel_launch(void* const* d_in, const int* in_sizes, int n_in,
                              void* d_out, int out_size, void* d_ws, size_t ws_size,
                              hipStream_t stream) {
  (void)in_sizes; (void)n_in; (void)out_size; (void)ws_size;
  const float* x = (const float*)d_in[0];
  const float* ipw = (const float*)d_in[1];
  const float* cw = (const float*)d_in[2];
  const float* cb = (const float*)d_in[3];
  const float* xpw = (const float*)d_in[4];
  const float* dtw = (const float*)d_in[5];
  const float* dtb = (const float*)d_in[6];
  const float* alog = (const float*)d_in[7];
  const float* dsv = (const float*)d_in[8];
  const float* ong = (const float*)d_in[9];
  const float* onb = (const float*)d_in[10];
  const float* opw = (const float*)d_in[11];

  float* ws = (float*)d_ws;
  float* xc = ws;    ws += BL * DI;
  float* zs = ws;    ws += BL * DI;
  float* xdl = ws;   ws += BL * DI;
  float* xtr = ws;   ws += BL * DI;
  float* Bsb = ws;   ws += BATCH * KK * LL * NST;
  float* Csb = ws;   ws += BATCH * KK * LL * NST;
  float* delta = ws; ws += BATCH * KK * DI * LL;
  float* oyp = ws;   ws += BATCH * KK * DI * LL;
  float* opwT = ws;  ws += DM * DI;

  hipLaunchKernelGGL(k_inproj, dim3(72 * 6), dim3(256), 0, stream, x, ipw, opw, xc, zs, opwT);
  hipLaunchKernelGGL(k_conv, dim3(72 * 24 * BATCH), dim3(256), 0, stream, xc, cw, cb, xdl);
  hipLaunchKernelGGL(k_tr, dim3(BATCH * DI), dim3(256), 0, stream, xdl, xtr);
  hipLaunchKernelGGL(k_xdbl, dim3(BATCH * KK * 36), dim3(256), 0, stream,
                     xdl, xtr, xpw, dtw, dtb, Bsb, Csb, delta);
  hipLaunchKernelGGL(k_scan, dim3(BATCH * KK * DI), dim3(1024), 0, stream,
                     delta, xdl, xtr, Bsb, Csb, alog, dsv, oyp);
  hipLaunchKernelGGL(k_final, dim3(BL), dim3(256), 0, stream, oyp, zs, ong, onb, opwT,
                     (float*)d_out);
}